// Round 4
// baseline (453.067 us; speedup 1.0000x reference)
//
#include <hip/hip_runtime.h>
#include <hip/hip_bf16.h>
#include <stdint.h>

#define B_ 4
#define T_ 2048
#define C_ 1024
#define H_ 16
#define D_ 64

typedef __attribute__((ext_vector_type(8))) short bf16x8;
typedef __attribute__((ext_vector_type(4))) short bf16x4;
typedef __attribute__((ext_vector_type(4))) float f32x4;

static __device__ __forceinline__ short f2bf(float f) {
    union { float f; unsigned u; } v; v.f = f;
    unsigned r = v.u + 0x7fffu + ((v.u >> 16) & 1u);
    return (short)(r >> 16);
}

#define GLD_LDS16(g, l) __builtin_amdgcn_global_load_lds( \
    (const __attribute__((address_space(1))) void*)(g),   \
    (__attribute__((address_space(3))) void*)(l), 16, 0, 0)

// ---------------------------------------------------------------------------
// Packing kernels
// ---------------------------------------------------------------------------
__global__ void pack_x(const float* __restrict__ x, short* __restrict__ xb) {
    int t = blockIdx.x * blockDim.x + threadIdx.x;
    const float* src = x + (size_t)t * 8;
    float4 v0 = *(const float4*)src;
    float4 v1 = *(const float4*)(src + 4);
    bf16x8 o;
    o[0] = f2bf(v0.x); o[1] = f2bf(v0.y); o[2] = f2bf(v0.z); o[3] = f2bf(v0.w);
    o[4] = f2bf(v1.x); o[5] = f2bf(v1.y); o[6] = f2bf(v1.z); o[7] = f2bf(v1.w);
    *(bf16x8*)(xb + (size_t)t * 8) = o;
}

// wq/wk/wv [H][C][D] fp32 -> wqkv_t [N=3072][K=1024] bf16 (B^T), n=qkv*1024+h*64+d
__global__ void pack_wqkv(const float* __restrict__ wq, const float* __restrict__ wk,
                          const float* __restrict__ wv, short* __restrict__ out) {
    int tid = blockIdx.x * blockDim.x + threadIdx.x;
    int n  = tid >> 7;
    int kc = tid & 127;
    int qkv = n >> 10;
    int h = (n >> 6) & 15;
    int d = n & 63;
    const float* w = (qkv == 0) ? wq : (qkv == 1) ? wk : wv;
    const float* src = w + (size_t)h * (C_ * D_) + d;
    short* dst = out + (size_t)n * C_ + kc * 8;
#pragma unroll
    for (int j = 0; j < 8; ++j)
        dst[j] = f2bf(src[(size_t)(kc * 8 + j) * D_]);
}

__global__ void pack_wproj(const float* __restrict__ wp, short* __restrict__ out) {
    int tid = blockIdx.x * blockDim.x + threadIdx.x;
    int n  = tid >> 7;
    int kc = tid & 127;
    short* dst = out + (size_t)n * C_ + kc * 8;
#pragma unroll
    for (int j = 0; j < 8; ++j)
        dst[j] = f2bf(wp[(size_t)(kc * 8 + j) * C_ + n]);
}

// ---------------------------------------------------------------------------
// GEMM (m97 structure): A[M][K] bf16, Bt[N][K] bf16, 128x128 tile, BK=32,
// global_load_lds width-16 staging, linear LDS. (bisect leg A: unchanged)
// ---------------------------------------------------------------------------
template<bool OUT_F32>
__global__ __launch_bounds__(256)
void gemm_lds(const short* __restrict__ A, const short* __restrict__ Bt,
              void* __restrict__ Cptr, const float* __restrict__ bias,
              int M, int N, int K) {
    __shared__ short As[128 * 32];
    __shared__ short Bs[128 * 32];
    const int tid = threadIdx.x;
    const int lane = tid & 63, wid = tid >> 6;
    const int wr = wid >> 1, wc = wid & 1;
    const int l15 = lane & 15, l4 = lane >> 4;
    const int m0 = blockIdx.y * 128, n0 = blockIdx.x * 128;

    f32x4 acc[4][4] = {};

    for (int k0 = 0; k0 < K; k0 += 32) {
#pragma unroll
        for (int p = 0; p < 2; ++p) {
            int e = p * 256 + tid;
            int r = e >> 2, c = e & 3;
            GLD_LDS16(A  + (size_t)(m0 + r) * K + k0 + c * 8, As + e * 8);
            GLD_LDS16(Bt + (size_t)(n0 + r) * K + k0 + c * 8, Bs + e * 8);
        }
        __syncthreads();
        bf16x8 af[4], bfr[4];
#pragma unroll
        for (int m = 0; m < 4; ++m)
            af[m] = *(const bf16x8*)(As + (wr * 64 + m * 16 + l15) * 32 + l4 * 8);
#pragma unroll
        for (int n = 0; n < 4; ++n)
            bfr[n] = *(const bf16x8*)(Bs + (wc * 64 + n * 16 + l15) * 32 + l4 * 8);
#pragma unroll
        for (int m = 0; m < 4; ++m)
#pragma unroll
            for (int n = 0; n < 4; ++n)
                acc[m][n] = __builtin_amdgcn_mfma_f32_16x16x32_bf16(af[m], bfr[n], acc[m][n], 0, 0, 0);
        __syncthreads();
    }

#pragma unroll
    for (int m = 0; m < 4; ++m) {
        int row_base = m0 + wr * 64 + m * 16 + l4 * 4;
#pragma unroll
        for (int n = 0; n < 4; ++n) {
            int col = n0 + wc * 64 + n * 16 + l15;
#pragma unroll
            for (int r = 0; r < 4; ++r) {
                int row = row_base + r;
                float v = acc[m][n][r];
                if (OUT_F32) {
                    ((float*)Cptr)[(size_t)row * N + col] = v + (bias ? bias[col] : 0.0f);
                } else {
                    ((short*)Cptr)[(size_t)row * N + col] = f2bf(v);
                }
            }
        }
    }
}

// ---------------------------------------------------------------------------
// Flash attention v3 (bisect leg B: round-1 proven structure).
// Deltas vs round 1: Q/K fragments direct from global (no Qs/Ks staging);
// V staged with coalesced bf16x8 loads + write-side transpose (8x ds_write_b16)
// into the round-1 Vt[64][72] layout. PV reads = round-1 ds_read_b128.
// ---------------------------------------------------------------------------
__global__ __launch_bounds__(256)
void attn_v3(const short* __restrict__ qkv, short* __restrict__ out) {
    const int qt = blockIdx.x;        // 0..31
    const int bh = blockIdx.y;        // 0..63
    const int b = bh >> 4;
    const int h = bh & 15;
    const int q0 = qt * 64;
    const int tid = threadIdx.x;
    const int wave = tid >> 6;
    const int lane = tid & 63;
    const int l15 = lane & 15, l4 = lane >> 4;

    __shared__ short Vt[64][72];      // Vt[d][s] = V[s][d]  (round-1 layout)
    __shared__ short Ps[4][16][72];   // per-wave P buffer   (round-1 layout)

    const size_t rs = 3 * C_;
    const short* qb = qkv + ((size_t)b * T_ + q0) * rs + h * 64;
    const short* kb = qkv + (size_t)b * T_ * rs + C_ + h * 64;
    const short* vb = qkv + (size_t)b * T_ * rs + 2 * C_ + h * 64;

    // Q fragments direct from global (A-frag: lane holds Q[l15][l4*8+j])
    bf16x8 aq0 = *(const bf16x8*)(qb + (size_t)(wave * 16 + l15) * rs + l4 * 8);
    bf16x8 aq1 = *(const bf16x8*)(qb + (size_t)(wave * 16 + l15) * rs + 32 + l4 * 8);

    f32x4 O[4] = {};
    float mrow[4], srow[4];
#pragma unroll
    for (int r = 0; r < 4; ++r) { mrow[r] = -1e30f; srow[r] = 0.0f; }

    const int nt = qt + 1;
    for (int t = 0; t < nt; ++t) {
        const int s0 = t * 64;
        __syncthreads();  // protect Vt from previous iteration's readers

        // ---- stage V: coalesced row loads + write-side transpose ----
#pragma unroll
        for (int p = 0; p < 2; ++p) {
            int e = p * 256 + tid;
            int s = e >> 3, d8 = e & 7;
            bf16x8 v = *(const bf16x8*)(vb + (size_t)(s0 + s) * rs + d8 * 8);
#pragma unroll
            for (int j = 0; j < 8; ++j)
                Vt[d8 * 8 + j][s] = v[j];
        }

        // K fragments direct from global (B-frag: lane holds K[n*16+l15][l4*8+j])
        bf16x8 bk0[4], bk1[4];
#pragma unroll
        for (int n = 0; n < 4; ++n) {
            const short* kr = kb + (size_t)(s0 + n * 16 + l15) * rs;
            bk0[n] = *(const bf16x8*)(kr + l4 * 8);
            bk1[n] = *(const bf16x8*)(kr + 32 + l4 * 8);
        }

        // ---- S = Q K^T ----
        f32x4 S[4];
#pragma unroll
        for (int n = 0; n < 4; ++n) {
            f32x4 z = {};
            z = __builtin_amdgcn_mfma_f32_16x16x32_bf16(aq0, bk0[n], z, 0, 0, 0);
            S[n] = __builtin_amdgcn_mfma_f32_16x16x32_bf16(aq1, bk1[n], z, 0, 0, 0);
        }

        // ---- scale + causal mask + row max ----
        const int qrow = q0 + wave * 16 + l4 * 4;  // + r
        const bool diag = (s0 == q0);
        float pmax[4];
#pragma unroll
        for (int r = 0; r < 4; ++r) pmax[r] = -1e30f;
#pragma unroll
        for (int n = 0; n < 4; ++n) {
#pragma unroll
            for (int r = 0; r < 4; ++r) {
                float v = S[n][r] * 0.03125f;
                if (diag) {
                    int scol = s0 + n * 16 + l15;
                    if (scol > qrow + r) v = -1e30f;
                }
                S[n][r] = v;
                pmax[r] = fmaxf(pmax[r], v);
            }
        }
#pragma unroll
        for (int r = 0; r < 4; ++r) {
            float v = pmax[r];
            v = fmaxf(v, __shfl_xor(v, 1));
            v = fmaxf(v, __shfl_xor(v, 2));
            v = fmaxf(v, __shfl_xor(v, 4));
            v = fmaxf(v, __shfl_xor(v, 8));
            pmax[r] = v;
        }

        // ---- online softmax update ----
        float psum[4];
#pragma unroll
        for (int r = 0; r < 4; ++r) {
            float mnew = fmaxf(mrow[r], pmax[r]);
            float fr = __expf(mrow[r] - mnew);
            mrow[r] = mnew;
            srow[r] *= fr;
#pragma unroll
            for (int n = 0; n < 4; ++n) O[n][r] *= fr;
            psum[r] = 0.0f;
        }
#pragma unroll
        for (int n = 0; n < 4; ++n) {
#pragma unroll
            for (int r = 0; r < 4; ++r) {
                float p = __expf(S[n][r] - mrow[r]);
                psum[r] += p;
                Ps[wave][l4 * 4 + r][n * 16 + l15] = f2bf(p);
            }
        }
#pragma unroll
        for (int r = 0; r < 4; ++r) {
            float v = psum[r];
            v += __shfl_xor(v, 1);
            v += __shfl_xor(v, 2);
            v += __shfl_xor(v, 4);
            v += __shfl_xor(v, 8);
            srow[r] += v;
        }

        __syncthreads();  // Vt fully staged; Ps writes also drained by barrier

        bf16x8 ap0 = *(const bf16x8*)&Ps[wave][l15][l4 * 8];
        bf16x8 ap1 = *(const bf16x8*)&Ps[wave][l15][32 + l4 * 8];

        // ---- O += P V  (round-1 verified read path) ----
#pragma unroll
        for (int n = 0; n < 4; ++n) {
            bf16x8 bv0 = *(const bf16x8*)&Vt[n * 16 + l15][l4 * 8];
            bf16x8 bv1 = *(const bf16x8*)&Vt[n * 16 + l15][32 + l4 * 8];
            O[n] = __builtin_amdgcn_mfma_f32_16x16x32_bf16(ap0, bv0, O[n], 0, 0, 0);
            O[n] = __builtin_amdgcn_mfma_f32_16x16x32_bf16(ap1, bv1, O[n], 0, 0, 0);
        }
    }

    // ---- normalize + store bf16 ----
#pragma unroll
    for (int r = 0; r < 4; ++r) {
        float inv = 1.0f / srow[r];
        int row = q0 + wave * 16 + l4 * 4 + r;
        size_t obase = ((size_t)b * T_ + row) * C_ + h * 64;
#pragma unroll
        for (int n = 0; n < 4; ++n)
            out[obase + n * 16 + l15] = f2bf(O[n][r] * inv);
    }
}

// ---------------------------------------------------------------------------
extern "C" void kernel_launch(void* const* d_in, const int* in_sizes, int n_in,
                              void* d_out, int out_size, void* d_ws, size_t ws_size,
                              hipStream_t stream) {
    const float* x     = (const float*)d_in[0];
    const float* wq    = (const float*)d_in[1];
    const float* wk    = (const float*)d_in[2];
    const float* wv    = (const float*)d_in[3];
    const float* wproj = (const float*)d_in[4];
    const float* bproj = (const float*)d_in[5];
    float* out = (float*)d_out;

    // workspace layout (shorts): wqkv_t | wproj_t | qkv | attn_b (also xb)
    short* wqkv_t  = (short*)d_ws;                  // 3072*1024
    short* wproj_t = wqkv_t + 3072 * 1024;          // 1024*1024
    short* qkv_b   = wproj_t + 1024 * 1024;         // 8192*3072
    short* attn_b  = qkv_b + (size_t)8192 * 3072;   // 8192*1024 (xb aliased here)
    short* xb      = attn_b;                        // x bf16, dead after gemm1
    // total = 75,497,472 bytes

    pack_x<<<4096, 256, 0, stream>>>(x, xb);
    pack_wqkv<<<1536, 256, 0, stream>>>(wq, wk, wv, wqkv_t);
    pack_wproj<<<512, 256, 0, stream>>>(wproj, wproj_t);

    // QKV projection: [8192,1024] x [1024,3072] -> bf16
    gemm_lds<false><<<dim3(24, 64), 256, 0, stream>>>(
        xb, wqkv_t, qkv_b, nullptr, 8192, 3072, 1024);

    // flash attention (overwrites attn_b; xb no longer needed)
    attn_v3<<<dim3(32, 64), 256, 0, stream>>>(qkv_b, attn_b);

    // output projection: [8192,1024] x [1024,1024] + bias -> fp32
    gemm_lds<true><<<dim3(8, 64), 256, 0, stream>>>(
        attn_b, wproj_t, out, bproj, 8192, 1024, 1024);
}

// Round 5
// 321.664 us; speedup vs baseline: 1.4085x; 1.4085x over previous
//
#include <hip/hip_runtime.h>
#include <hip/hip_bf16.h>
#include <stdint.h>

#define B_ 4
#define T_ 2048
#define C_ 1024
#define H_ 16
#define D_ 64

typedef __attribute__((ext_vector_type(8))) short bf16x8;
typedef __attribute__((ext_vector_type(4))) float f32x4;

static __device__ __forceinline__ short f2bf(float f) {
    union { float f; unsigned u; } v; v.f = f;
    unsigned r = v.u + 0x7fffu + ((v.u >> 16) & 1u);
    return (short)(r >> 16);
}

#define GLD_LDS16(g, l) __builtin_amdgcn_global_load_lds( \
    (const __attribute__((address_space(1))) void*)(g),   \
    (__attribute__((address_space(3))) void*)(l), 16, 0, 0)

// ---------------------------------------------------------------------------
// Packing kernels
// ---------------------------------------------------------------------------
__global__ void pack_x(const float* __restrict__ x, short* __restrict__ xb) {
    int t = blockIdx.x * blockDim.x + threadIdx.x;
    const float* src = x + (size_t)t * 8;
    float4 v0 = *(const float4*)src;
    float4 v1 = *(const float4*)(src + 4);
    bf16x8 o;
    o[0] = f2bf(v0.x); o[1] = f2bf(v0.y); o[2] = f2bf(v0.z); o[3] = f2bf(v0.w);
    o[4] = f2bf(v1.x); o[5] = f2bf(v1.y); o[6] = f2bf(v1.z); o[7] = f2bf(v1.w);
    *(bf16x8*)(xb + (size_t)t * 8) = o;
}

// wq/wk/wv [H][C][D] fp32 -> wqkv_t [N=3072][K=1024] bf16 (B^T), n=qkv*1024+h*64+d
__global__ void pack_wqkv(const float* __restrict__ wq, const float* __restrict__ wk,
                          const float* __restrict__ wv, short* __restrict__ out) {
    int tid = blockIdx.x * blockDim.x + threadIdx.x;
    int n  = tid >> 7;
    int kc = tid & 127;
    int qkv = n >> 10;
    int h = (n >> 6) & 15;
    int d = n & 63;
    const float* w = (qkv == 0) ? wq : (qkv == 1) ? wk : wv;
    const float* src = w + (size_t)h * (C_ * D_) + d;
    short* dst = out + (size_t)n * C_ + kc * 8;
#pragma unroll
    for (int j = 0; j < 8; ++j)
        dst[j] = f2bf(src[(size_t)(kc * 8 + j) * D_]);
}

__global__ void pack_wproj(const float* __restrict__ wp, short* __restrict__ out) {
    int tid = blockIdx.x * blockDim.x + threadIdx.x;
    int n  = tid >> 7;
    int kc = tid & 127;
    short* dst = out + (size_t)n * C_ + kc * 8;
#pragma unroll
    for (int j = 0; j < 8; ++j)
        dst[j] = f2bf(wp[(size_t)(kc * 8 + j) * C_ + n]);
}

// ---------------------------------------------------------------------------
// GEMM (m97 structure): unchanged, passed in round 4.
// ---------------------------------------------------------------------------
template<bool OUT_F32>
__global__ __launch_bounds__(256)
void gemm_lds(const short* __restrict__ A, const short* __restrict__ Bt,
              void* __restrict__ Cptr, const float* __restrict__ bias,
              int M, int N, int K) {
    __shared__ short As[128 * 32];
    __shared__ short Bs[128 * 32];
    const int tid = threadIdx.x;
    const int lane = tid & 63, wid = tid >> 6;
    const int wr = wid >> 1, wc = wid & 1;
    const int l15 = lane & 15, l4 = lane >> 4;
    const int m0 = blockIdx.y * 128, n0 = blockIdx.x * 128;

    f32x4 acc[4][4] = {};

    for (int k0 = 0; k0 < K; k0 += 32) {
#pragma unroll
        for (int p = 0; p < 2; ++p) {
            int e = p * 256 + tid;
            int r = e >> 2, c = e & 3;
            GLD_LDS16(A  + (size_t)(m0 + r) * K + k0 + c * 8, As + e * 8);
            GLD_LDS16(Bt + (size_t)(n0 + r) * K + k0 + c * 8, Bs + e * 8);
        }
        __syncthreads();
        bf16x8 af[4], bfr[4];
#pragma unroll
        for (int m = 0; m < 4; ++m)
            af[m] = *(const bf16x8*)(As + (wr * 64 + m * 16 + l15) * 32 + l4 * 8);
#pragma unroll
        for (int n = 0; n < 4; ++n)
            bfr[n] = *(const bf16x8*)(Bs + (wc * 64 + n * 16 + l15) * 32 + l4 * 8);
#pragma unroll
        for (int m = 0; m < 4; ++m)
#pragma unroll
            for (int n = 0; n < 4; ++n)
                acc[m][n] = __builtin_amdgcn_mfma_f32_16x16x32_bf16(af[m], bfr[n], acc[m][n], 0, 0, 0);
        __syncthreads();
    }

#pragma unroll
    for (int m = 0; m < 4; ++m) {
        int row_base = m0 + wr * 64 + m * 16 + l4 * 4;
#pragma unroll
        for (int n = 0; n < 4; ++n) {
            int col = n0 + wc * 64 + n * 16 + l15;
#pragma unroll
            for (int r = 0; r < 4; ++r) {
                int row = row_base + r;
                float v = acc[m][n][r];
                if (OUT_F32) {
                    ((float*)Cptr)[(size_t)row * N + col] = v + (bias ? bias[col] : 0.0f);
                } else {
                    ((short*)Cptr)[(size_t)row * N + col] = f2bf(v);
                }
            }
        }
    }
}

// ---------------------------------------------------------------------------
// Flash attention v5: causal-paired strips.
// Block pi in 0..15 handles q-strip A (qt=pi) and strip B (qt=31-pi).
// K fragments + V tile staged ONCE per kv-tile, shared by both strips.
// V staging = round-1 proven gather; softmax/Ps = round-1 proven path.
// ---------------------------------------------------------------------------
__device__ __forceinline__ void softmax_pv_phase1(
    f32x4 S[4], f32x4 O[4], float* mrow, float* srow,
    int qrow0, int s0, bool diag, int l15, int l4, short* ps) {
    float pmax[4];
#pragma unroll
    for (int r = 0; r < 4; ++r) pmax[r] = -1e30f;
#pragma unroll
    for (int n = 0; n < 4; ++n) {
#pragma unroll
        for (int r = 0; r < 4; ++r) {
            float v = S[n][r] * 0.03125f;
            if (diag) {
                int scol = s0 + n * 16 + l15;
                if (scol > qrow0 + r) v = -1e30f;
            }
            S[n][r] = v;
            pmax[r] = fmaxf(pmax[r], v);
        }
    }
#pragma unroll
    for (int r = 0; r < 4; ++r) {
        float v = pmax[r];
        v = fmaxf(v, __shfl_xor(v, 1));
        v = fmaxf(v, __shfl_xor(v, 2));
        v = fmaxf(v, __shfl_xor(v, 4));
        v = fmaxf(v, __shfl_xor(v, 8));
        pmax[r] = v;
    }
    float psum[4];
#pragma unroll
    for (int r = 0; r < 4; ++r) {
        float mnew = fmaxf(mrow[r], pmax[r]);
        float fr = __expf(mrow[r] - mnew);
        mrow[r] = mnew;
        srow[r] *= fr;
#pragma unroll
        for (int n = 0; n < 4; ++n) O[n][r] *= fr;
        psum[r] = 0.0f;
    }
#pragma unroll
    for (int n = 0; n < 4; ++n) {
#pragma unroll
        for (int r = 0; r < 4; ++r) {
            float p = __expf(S[n][r] - mrow[r]);
            psum[r] += p;
            ps[(l4 * 4 + r) * 72 + n * 16 + l15] = f2bf(p);
        }
    }
#pragma unroll
    for (int r = 0; r < 4; ++r) {
        float v = psum[r];
        v += __shfl_xor(v, 1);
        v += __shfl_xor(v, 2);
        v += __shfl_xor(v, 4);
        v += __shfl_xor(v, 8);
        srow[r] += v;
    }
}

__global__ __launch_bounds__(256)
void attn_v5(const short* __restrict__ qkv, short* __restrict__ out) {
    const int pi = blockIdx.x;        // 0..15  (strip pair)
    const int bh = blockIdx.y;        // 0..63
    const int b = bh >> 4;
    const int h = bh & 15;
    const int qA0 = pi * 64;          // strip A (early rows)
    const int qB0 = (31 - pi) * 64;   // strip B (late rows)
    const int ntA = pi + 1;
    const int ntB = 32 - pi;
    const int tid = threadIdx.x;
    const int wave = tid >> 6;
    const int lane = tid & 63;
    const int l15 = lane & 15, l4 = lane >> 4;

    __shared__ short Vt[64][72];        // Vt[d][s] = V[s][d]
    __shared__ short Ps[4][2][16][72];  // per-wave, per-strip P buffer

    const size_t rs = 3 * C_;
    const short* qbA = qkv + ((size_t)b * T_ + qA0) * rs + h * 64;
    const short* qbB = qkv + ((size_t)b * T_ + qB0) * rs + h * 64;
    const short* kb  = qkv + (size_t)b * T_ * rs + C_ + h * 64;
    const short* vb  = qkv + (size_t)b * T_ * rs + 2 * C_ + h * 64;

    // Q fragments (A-frag: lane holds Q[l15][l4*8+j]) for both strips
    bf16x8 aqA0 = *(const bf16x8*)(qbA + (size_t)(wave * 16 + l15) * rs + l4 * 8);
    bf16x8 aqA1 = *(const bf16x8*)(qbA + (size_t)(wave * 16 + l15) * rs + 32 + l4 * 8);
    bf16x8 aqB0 = *(const bf16x8*)(qbB + (size_t)(wave * 16 + l15) * rs + l4 * 8);
    bf16x8 aqB1 = *(const bf16x8*)(qbB + (size_t)(wave * 16 + l15) * rs + 32 + l4 * 8);

    f32x4 OA[4] = {}, OB[4] = {};
    float mA[4], sA[4], mB[4], sB[4];
#pragma unroll
    for (int r = 0; r < 4; ++r) { mA[r] = mB[r] = -1e30f; sA[r] = sB[r] = 0.0f; }

    short* psB = &Ps[wave][0][0][0];
    short* psA = &Ps[wave][1][0][0];

    for (int t = 0; t < ntB; ++t) {
        const int s0 = t * 64;
        const bool actA = (t < ntA);
        __syncthreads();  // all waves done reading Vt from previous tile

        // ---- stage V (round-1 gather: coalesced loads, b128 row writes) ----
#pragma unroll
        for (int p = 0; p < 2; ++p) {
            int e = p * 256 + tid;
            int d = e & 63, sc = e >> 6;
            bf16x8 v;
#pragma unroll
            for (int j = 0; j < 8; ++j)
                v[j] = vb[(size_t)(s0 + sc * 8 + j) * rs + d];
            *(bf16x8*)&Vt[d][sc * 8] = v;
        }

        // ---- K fragments, shared by both strips ----
        bf16x8 bk0[4], bk1[4];
#pragma unroll
        for (int n = 0; n < 4; ++n) {
            const short* kr = kb + (size_t)(s0 + n * 16 + l15) * rs;
            bk0[n] = *(const bf16x8*)(kr + l4 * 8);
            bk1[n] = *(const bf16x8*)(kr + 32 + l4 * 8);
        }

        // ---- strip B: S = Q K^T, softmax, P->LDS ----
        f32x4 S[4];
#pragma unroll
        for (int n = 0; n < 4; ++n) {
            f32x4 z = {};
            z = __builtin_amdgcn_mfma_f32_16x16x32_bf16(aqB0, bk0[n], z, 0, 0, 0);
            S[n] = __builtin_amdgcn_mfma_f32_16x16x32_bf16(aqB1, bk1[n], z, 0, 0, 0);
        }
        softmax_pv_phase1(S, OB, mB, sB, qB0 + wave * 16 + l4 * 4, s0,
                          s0 == qB0, l15, l4, psB);

        // ---- strip A (while active) ----
        if (actA) {
            f32x4 SA[4];
#pragma unroll
            for (int n = 0; n < 4; ++n) {
                f32x4 z = {};
                z = __builtin_amdgcn_mfma_f32_16x16x32_bf16(aqA0, bk0[n], z, 0, 0, 0);
                SA[n] = __builtin_amdgcn_mfma_f32_16x16x32_bf16(aqA1, bk1[n], z, 0, 0, 0);
            }
            softmax_pv_phase1(SA, OA, mA, sA, qA0 + wave * 16 + l4 * 4, s0,
                              s0 == qA0, l15, l4, psA);
        }

        __syncthreads();  // Vt staged; Ps writes drained by barrier

        // ---- PV for strip B ----
        bf16x8 apB0 = *(const bf16x8*)(psB + l15 * 72 + l4 * 8);
        bf16x8 apB1 = *(const bf16x8*)(psB + l15 * 72 + 32 + l4 * 8);
#pragma unroll
        for (int n = 0; n < 4; ++n) {
            bf16x8 bv0 = *(const bf16x8*)&Vt[n * 16 + l15][l4 * 8];
            bf16x8 bv1 = *(const bf16x8*)&Vt[n * 16 + l15][32 + l4 * 8];
            OB[n] = __builtin_amdgcn_mfma_f32_16x16x32_bf16(apB0, bv0, OB[n], 0, 0, 0);
            OB[n] = __builtin_amdgcn_mfma_f32_16x16x32_bf16(apB1, bv1, OB[n], 0, 0, 0);
        }
        // ---- PV for strip A ----
        if (actA) {
            bf16x8 apA0 = *(const bf16x8*)(psA + l15 * 72 + l4 * 8);
            bf16x8 apA1 = *(const bf16x8*)(psA + l15 * 72 + 32 + l4 * 8);
#pragma unroll
            for (int n = 0; n < 4; ++n) {
                bf16x8 bv0 = *(const bf16x8*)&Vt[n * 16 + l15][l4 * 8];
                bf16x8 bv1 = *(const bf16x8*)&Vt[n * 16 + l15][32 + l4 * 8];
                OA[n] = __builtin_amdgcn_mfma_f32_16x16x32_bf16(apA0, bv0, OA[n], 0, 0, 0);
                OA[n] = __builtin_amdgcn_mfma_f32_16x16x32_bf16(apA1, bv1, OA[n], 0, 0, 0);
            }
        }
    }

    // ---- normalize + store both strips ----
#pragma unroll
    for (int r = 0; r < 4; ++r) {
        int rowB = qB0 + wave * 16 + l4 * 4 + r;
        int rowA = qA0 + wave * 16 + l4 * 4 + r;
        float invB = 1.0f / sB[r];
        float invA = 1.0f / sA[r];
        size_t obB = ((size_t)b * T_ + rowB) * C_ + h * 64;
        size_t obA = ((size_t)b * T_ + rowA) * C_ + h * 64;
#pragma unroll
        for (int n = 0; n < 4; ++n) {
            out[obB + n * 16 + l15] = f2bf(OB[n][r] * invB);
            out[obA + n * 16 + l15] = f2bf(OA[n][r] * invA);
        }
    }
}

// ---------------------------------------------------------------------------
extern "C" void kernel_launch(void* const* d_in, const int* in_sizes, int n_in,
                              void* d_out, int out_size, void* d_ws, size_t ws_size,
                              hipStream_t stream) {
    const float* x     = (const float*)d_in[0];
    const float* wq    = (const float*)d_in[1];
    const float* wk    = (const float*)d_in[2];
    const float* wv    = (const float*)d_in[3];
    const float* wproj = (const float*)d_in[4];
    const float* bproj = (const float*)d_in[5];
    float* out = (float*)d_out;

    // workspace layout (shorts): wqkv_t | wproj_t | qkv | attn_b (also xb)
    short* wqkv_t  = (short*)d_ws;                  // 3072*1024
    short* wproj_t = wqkv_t + 3072 * 1024;          // 1024*1024
    short* qkv_b   = wproj_t + 1024 * 1024;         // 8192*3072
    short* attn_b  = qkv_b + (size_t)8192 * 3072;   // 8192*1024 (xb aliased here)
    short* xb      = attn_b;                        // x bf16, dead after gemm1
    // total = 75,497,472 bytes

    pack_x<<<4096, 256, 0, stream>>>(x, xb);
    pack_wqkv<<<1536, 256, 0, stream>>>(wq, wk, wv, wqkv_t);
    pack_wproj<<<512, 256, 0, stream>>>(wproj, wproj_t);

    // QKV projection: [8192,1024] x [1024,3072] -> bf16
    gemm_lds<false><<<dim3(24, 64), 256, 0, stream>>>(
        xb, wqkv_t, qkv_b, nullptr, 8192, 3072, 1024);

    // flash attention, causal-paired strips
    attn_v5<<<dim3(16, 64), 256, 0, stream>>>(qkv_b, attn_b);

    // output projection: [8192,1024] x [1024,1024] + bias -> fp32
    gemm_lds<true><<<dim3(8, 64), 256, 0, stream>>>(
        attn_b, wproj_t, out, bproj, 8192, 1024, 1024);
}